// Round 8
// baseline (280.023 us; speedup 1.0000x reference)
//
#include <hip/hip_runtime.h>
#include <stdint.h>

typedef unsigned short u16;
typedef __attribute__((ext_vector_type(4))) float f32x4;
typedef __attribute__((ext_vector_type(8))) short bf16x8;
typedef __attribute__((ext_vector_type(4))) int i32x4;

#define LOG2E 1.4426950408889634f

// fp32 -> bf16 round-to-nearest-even
__device__ inline u16 f2b(float x) {
  union { float f; uint32_t u; } t; t.f = x;
  uint32_t r = t.u + 0x7FFFu + ((t.u >> 16) & 1u);
  return (u16)(r >> 16);
}

// packed fp32 pair -> bf16 pair (1 VALU op)
__device__ inline int cvtpk(float a, float b) {
  int r;
  asm("v_cvt_pk_bf16_f32 %0, %1, %2" : "=v"(r) : "v"(a), "v"(b));
  return r;
}

// 2^x via v_exp_f32
__device__ inline float exp2a(float x) {
  float r;
  asm("v_exp_f32 %0, %1" : "=v"(r) : "v"(x));
  return r;
}

// async global->LDS 16B DMA; LDS dest linear (wave base + lane*16)
typedef const __attribute__((address_space(1))) void* gas_t;
typedef __attribute__((address_space(3))) void* las_t;
__device__ inline void gld16(const void* g, void* l) {
  __builtin_amdgcn_global_load_lds((gas_t)g, (las_t)l, 16, 0, 0);
}

// ---------------- kernel 1: hidden_states fp32 -> bf16 ----------------
__global__ void cvt_hs_k(const float* __restrict__ in, u16* __restrict__ outp, int n) {
  int i = (blockIdx.x * 256 + threadIdx.x) * 4;
  if (i >= n) return;
  float4 v = *(const float4*)(in + i);
  ushort4 o = { f2b(v.x), f2b(v.y), f2b(v.z), f2b(v.w) };
  *(ushort4*)(outp + i) = o;
}

// ---------------- kernel 2: W [k][n] fp32 -> Wt [n][k] bf16 (x3) ----------------
__global__ void twk(const float* __restrict__ Wq, const float* __restrict__ Wk,
                    const float* __restrict__ Wv, u16* __restrict__ Wt) {
  __shared__ float tile[64][65];
  const float* W = (blockIdx.z == 0) ? Wq : ((blockIdx.z == 1) ? Wk : Wv);
  int n0 = blockIdx.x * 64, k0 = blockIdx.y * 64;
  int tid = threadIdx.x;
#pragma unroll 4
  for (int i = 0; i < 16; ++i) {
    int idx = i * 256 + tid; int r = idx >> 6, c = idx & 63;
    tile[r][c] = W[(k0 + r) * 1024 + n0 + c];
  }
  __syncthreads();
  u16* dst = Wt + blockIdx.z * 1048576;
#pragma unroll 4
  for (int i = 0; i < 16; ++i) {
    int idx = i * 256 + tid; int r = idx >> 6, c = idx & 63;
    dst[(n0 + r) * 1024 + k0 + c] = f2b(tile[c][r]);
  }
}

// ---------------- kernel 3: QKV GEMM 128x128, BK=32, dbuf counted-vmcnt ----------
// 4 waves (2Mx2N), wave tile 64x64, 32 K-iters, LDS 32 KB -> 4 blocks/CU.
// 2-row-packed LDS: tile row r lives at [r>>1][ (r&1)*4 | slot ], slot c XOR'd
// by (r>>1)&3 -> 128B LDS rows, 8 distinct 16B slots x 8 lanes (conflict-floor).
// Stage via gld16 linear dest + inverse-swizzled global source.
__global__ __launch_bounds__(256) void qkv_gemm_k(
    const u16* __restrict__ hsb, const u16* __restrict__ wt,
    const float* __restrict__ bq, const float* __restrict__ bk, const float* __restrict__ bv,
    u16* __restrict__ Qo, u16* __restrict__ Ko, u16* __restrict__ Vto) {
  __shared__ u16 lh[2][128 * 32];   // 8 KB each
  __shared__ u16 lw[2][128 * 32];
  const int tid = threadIdx.x;
  const int w = tid >> 6, l = tid & 63, g = l >> 4, lm = l & 15;
  const int wm = w >> 1, wn = w & 1;

  // XCD bijective swizzle: nwg = 24*64 = 1536 = 8*192, by-major chunks
  int lin = blockIdx.y * 24 + blockIdx.x;
  lin = (lin & 7) * 192 + (lin >> 3);
  const int bx = lin % 24, by = lin / 24;
  const int nbase = bx << 7;              // 0..3071 over {q,k,v}
  const int wi = nbase >> 10;             // 0=q 1=k 2=v
  const int nloc0 = nbase & 1023;
  const int mbase = by << 7;
  const u16* hsg = hsb + (size_t)mbase * 1024;
  const u16* wg  = wt + (size_t)wi * 1048576 + (size_t)nloc0 * 1024;

  f32x4 acc[4][4];
#pragma unroll
  for (int i = 0; i < 4; ++i)
#pragma unroll
    for (int j = 0; j < 4; ++j)
#pragma unroll
      for (int r = 0; r < 4; ++r) acc[i][j][r] = 0.f;

  // stage mapping: idx in [0,512): r2=idx>>3, slot=idx&7 ->
  //   global row r=r2*2+(slot>>2), chunk c=(slot&3)^(r2&3); dest = idx*16B
  const int i0 = tid, i1 = tid + 256;
  const int r0 = ((i0 >> 3) << 1) + ((i0 >> 2) & 1), c0 = ((i0 & 3) ^ ((i0 >> 3) & 3)) << 3;
  const int r1 = ((i1 >> 3) << 1) + ((i1 >> 2) & 1), c1 = ((i1 & 3) ^ ((i1 >> 3) & 3)) << 3;

  // frag read offsets (u16 units): row r -> (r>>1)*64 + slot*8, slot lane-const
  const int so = (((lm & 1) << 2) + (g ^ ((lm >> 1) & 3))) << 3;
  const int fbm = (wm * 32 + (lm >> 1)) * 64 + so;   // + mi*512
  const int fbn = (wn * 32 + (lm >> 1)) * 64 + so;   // + ni*512

  // prologue: stage K-tile 0 into buf 0
  gld16(hsg + (size_t)r0 * 1024 + c0, &lh[0][i0 * 8]);
  gld16(hsg + (size_t)r1 * 1024 + c1, &lh[0][i1 * 8]);
  gld16(wg + (size_t)r0 * 1024 + c0, &lw[0][i0 * 8]);
  gld16(wg + (size_t)r1 * 1024 + c1, &lw[0][i1 * 8]);

  for (int t = 0; t < 32; ++t) {
    const int cur = t & 1;
    if (t < 31) {
      const int kb = (t + 1) << 5;
      gld16(hsg + (size_t)r0 * 1024 + kb + c0, &lh[cur ^ 1][i0 * 8]);
      gld16(hsg + (size_t)r1 * 1024 + kb + c1, &lh[cur ^ 1][i1 * 8]);
      gld16(wg + (size_t)r0 * 1024 + kb + c0, &lw[cur ^ 1][i0 * 8]);
      gld16(wg + (size_t)r1 * 1024 + kb + c1, &lw[cur ^ 1][i1 * 8]);
      asm volatile("s_waitcnt vmcnt(4)" ::: "memory");   // stage(t) landed; t+1 flies
    } else {
      asm volatile("s_waitcnt vmcnt(0)" ::: "memory");
    }
    __builtin_amdgcn_s_barrier();           // BAR1

    const u16* LH = lh[cur];
    const u16* LW = lw[cur];
    bf16x8 fh[4], fw[4];
#pragma unroll
    for (int i = 0; i < 4; ++i) {
      fh[i] = *(const bf16x8*)(LH + fbm + i * 512);
      fw[i] = *(const bf16x8*)(LW + fbn + i * 512);
    }
    __builtin_amdgcn_s_setprio(1);
    if (wi < 2) {
#pragma unroll
      for (int mi = 0; mi < 4; ++mi)
#pragma unroll
        for (int ni = 0; ni < 4; ++ni)
          acc[mi][ni] = __builtin_amdgcn_mfma_f32_16x16x32_bf16(fw[ni], fh[mi], acc[mi][ni], 0, 0, 0);
    } else {
#pragma unroll
      for (int mi = 0; mi < 4; ++mi)
#pragma unroll
        for (int ni = 0; ni < 4; ++ni)
          acc[mi][ni] = __builtin_amdgcn_mfma_f32_16x16x32_bf16(fh[mi], fw[ni], acc[mi][ni], 0, 0, 0);
    }
    __builtin_amdgcn_s_setprio(0);
    __builtin_amdgcn_s_barrier();           // BAR2: buf[cur] reads closed
  }

  if (wi < 2) {
    u16* O = (wi == 0) ? Qo : Ko;
    const float* bias = (wi == 0) ? bq : bk;
#pragma unroll
    for (int ni = 0; ni < 4; ++ni) {
      int nl = nloc0 + wn * 64 + ni * 16 + g * 4;   // 4 consecutive n = d
      f32x4 b4 = *(const f32x4*)(bias + nl);
      int d = nl & 63, h = nl >> 6;
#pragma unroll
      for (int mi = 0; mi < 4; ++mi) {
        int m = mbase + wm * 64 + mi * 16 + lm;
        int bb = m >> 11, s = m & 2047;
        f32x4 v = acc[mi][ni];
        int2 o = { cvtpk(v[0] + b4[0], v[1] + b4[1]), cvtpk(v[2] + b4[2], v[3] + b4[3]) };
        *(int2*)(O + ((size_t)(bb * 16 + h) * 2048 + s) * 64 + d) = o;
      }
    }
  } else {
#pragma unroll
    for (int ni = 0; ni < 4; ++ni) {
      int nl = nloc0 + wn * 64 + ni * 16 + lm;
      float bsc = bv[nl];
      int d = nl & 63, h = nl >> 6;
#pragma unroll
      for (int mi = 0; mi < 4; ++mi) {
        int m = mbase + wm * 64 + mi * 16 + g * 4;  // 4 consecutive m = s
        int bb = m >> 11, s = m & 2047;
        int cp = (s & ~31) | (((s >> 2) & 3) << 3) | (((s >> 4) & 1) << 2);
        f32x4 v = acc[mi][ni];
        int2 o = { cvtpk(v[0] + bsc, v[1] + bsc), cvtpk(v[2] + bsc, v[3] + bsc) };
        *(int2*)(Vto + ((size_t)(bb * 16 + h) * 64 + d) * 2048 + cp) = o;
      }
    }
  }
}

// ---------------- kernel 4: flash attention, cross-tile pipelined ----------------
// iter t: [stage V(t+1),K(t+2)] [QK(t+1) on MFMA pipe] [softmax(t) on VALU,
// independent] [PV(t)]. K/V = 2-slot rings, V staged one phase late; peeled
// t=30/31 tail. Fixed-max softmax (R6, validated).
__global__ __launch_bounds__(512) void attn_k(
    const u16* __restrict__ Qg, const u16* __restrict__ Kg, const u16* __restrict__ Vtg,
    const float* __restrict__ maskg, float* __restrict__ outp) {
  __shared__ u16 kts[2][64 * 64];   // [sk 64][d 64], source-XOR'd (8 KB each)
  __shared__ u16 vts[2][64 * 64];   // [d 64][c' 64], source-XOR'd
  __shared__ float ml[2048];        // mask*LOG2E - 8
  const int tid = threadIdx.x;
  const int w = tid >> 6, l = tid & 63, g = l >> 4, lm = l & 15;

  int bid = blockIdx.y * 16 + blockIdx.x;
  bid = (bid & 7) * 128 + (bid >> 3);
  const int bx = bid & 15, bh = bid >> 4;
  const int b = bh >> 4, h = bh & 15;
  const int q0 = bx * 128 + w * 16;
  const u16* Qb = Qg + ((size_t)bh * 2048 + q0) * 64;
  const u16* Kb = Kg + (size_t)bh * 2048 * 64;
  const u16* Vb = Vtg + (size_t)bh * 64 * 2048;
  const float* mb = maskg + b * 2048;

  bf16x8 qf0 = *(const bf16x8*)(Qb + lm * 64 + g * 8);
  bf16x8 qf1 = *(const bf16x8*)(Qb + lm * 64 + 32 + g * 8);

  f32x4 ctx[4];
#pragma unroll
  for (int dt = 0; dt < 4; ++dt)
#pragma unroll
    for (int r = 0; r < 4; ++r) ctx[dt][r] = 0.f;
  float lrun = 0.f;
  const float QS = 0.125f * LOG2E;
  const f32x4 zf = { 0.f, 0.f, 0.f, 0.f };

  const int key = lm & 7;
  const int fb0 = lm * 64 + ((g ^ key) << 3);
  const int fb1 = lm * 64 + (((g + 4) ^ key) << 3);
  const float* mlb = ml + g * 4;

  const int rk = tid >> 3, ck = tid & 7;
  const int swz = (ck ^ (rk & 7)) << 3;

#define QK_BLOCK(KT, ST)                                                        \
  do {                                                                          \
    __builtin_amdgcn_s_setprio(1);                                              \
    _Pragma("unroll") for (int t8 = 0; t8 < 4; ++t8) {                          \
      bf16x8 kf = *(const bf16x8*)((KT) + t8 * 1024 + fb0);                     \
      ST[t8] = __builtin_amdgcn_mfma_f32_16x16x32_bf16(kf, qf0, zf, 0, 0, 0);   \
    }                                                                           \
    _Pragma("unroll") for (int t8 = 0; t8 < 4; ++t8) {                          \
      bf16x8 kf = *(const bf16x8*)((KT) + t8 * 1024 + fb1);                     \
      ST[t8] = __builtin_amdgcn_mfma_f32_16x16x32_bf16(kf, qf1, ST[t8], 0, 0, 0);\
    }                                                                           \
    __builtin_amdgcn_s_setprio(0);                                              \
  } while (0)

#define SM_BLOCK(ST, KV)                                                        \
  do {                                                                          \
    _Pragma("unroll") for (int t8 = 0; t8 < 4; ++t8) {                          \
      f32x4 mv = *(const f32x4*)(mlb + (KV) + t8 * 16);                         \
      float p0 = exp2a(fmaf(ST[t8][0], QS, mv[0]));                             \
      float p1 = exp2a(fmaf(ST[t8][1], QS, mv[1]));                             \
      float p2 = exp2a(fmaf(ST[t8][2], QS, mv[2]));                             \
      float p3 = exp2a(fmaf(ST[t8][3], QS, mv[3]));                             \
      lrun += (p0 + p1) + (p2 + p3);                                            \
      pt[t8][0] = cvtpk(p0, p1);                                                \
      pt[t8][1] = cvtpk(p2, p3);                                                \
    }                                                                           \
  } while (0)

#define PV_BLOCK(VT)                                                            \
  do {                                                                          \
    __builtin_amdgcn_s_setprio(1);                                              \
    _Pragma("unroll") for (int tp = 0; tp < 2; ++tp) {                          \
      i32x4 pbi = { pt[2 * tp][0], pt[2 * tp][1],                               \
                    pt[2 * tp + 1][0], pt[2 * tp + 1][1] };                     \
      bf16x8 pb = __builtin_bit_cast(bf16x8, pbi);                              \
      const int fb = tp ? fb1 : fb0;                                            \
      _Pragma("unroll") for (int dt = 0; dt < 4; ++dt) {                        \
        bf16x8 va = *(const bf16x8*)((VT) + dt * 1024 + fb);                    \
        ctx[dt] = __builtin_amdgcn_mfma_f32_16x16x32_bf16(va, pb, ctx[dt], 0, 0, 0);\
      }                                                                         \
    }                                                                           \
    __builtin_amdgcn_s_setprio(0);                                              \
  } while (0)

  // prologue: mask row, K0, V0, K1; full drain; QK(0); barrier closes K0 reads
  {
    f32x4 mv = *(const f32x4*)(mb + tid * 4);
    *(f32x4*)(ml + tid * 4) = mv * LOG2E - 8.0f;
  }
  gld16(Kb + (size_t)rk * 64 + swz, &kts[0][tid * 8]);
  gld16(Vb + (size_t)rk * 2048 + swz, &vts[0][tid * 8]);
  gld16(Kb + (size_t)(64 + rk) * 64 + swz, &kts[1][tid * 8]);
  __syncthreads();

  f32x4 stp[4];
  QK_BLOCK(kts[0], stp);
  __builtin_amdgcn_s_barrier();     // close QK(0) reads before K2 staging

  int pt[4][2];
  for (int t = 0; t < 30; ++t) {
    const int cur = t & 1;
    gld16(Vb + (size_t)rk * 2048 + ((t + 1) << 6) + swz, &vts[cur ^ 1][tid * 8]);
    gld16(Kb + (size_t)(((t + 2) << 6) + rk) * 64 + swz, &kts[cur][tid * 8]);
    asm volatile("s_waitcnt vmcnt(2)" ::: "memory");   // K(t+1),V(t) landed
    __builtin_amdgcn_s_barrier();   // BAR1

    f32x4 stn[4];
    QK_BLOCK(kts[cur ^ 1], stn);    // QK(t+1), result used next iter
    __builtin_amdgcn_sched_barrier(0);
    SM_BLOCK(stp, t << 6);          // softmax(t): independent of QK MFMAs
    PV_BLOCK(vts[cur]);             // PV(t)
#pragma unroll
    for (int t8 = 0; t8 < 4; ++t8) stp[t8] = stn[t8];
    __builtin_amdgcn_s_barrier();   // BAR2
  }
  { // t = 30: stage V31 only
    gld16(Vb + (size_t)rk * 2048 + (31 << 6) + swz, &vts[1][tid * 8]);
    asm volatile("s_waitcnt vmcnt(1)" ::: "memory");
    __builtin_amdgcn_s_barrier();
    f32x4 stn[4];
    QK_BLOCK(kts[1], stn);
    __builtin_amdgcn_sched_barrier(0);
    SM_BLOCK(stp, 30 << 6);
    PV_BLOCK(vts[0]);
#pragma unroll
    for (int t8 = 0; t8 < 4; ++t8) stp[t8] = stn[t8];
    __builtin_amdgcn_s_barrier();
  }
  { // t = 31
    asm volatile("s_waitcnt vmcnt(0)" ::: "memory");
    __builtin_amdgcn_s_barrier();
    SM_BLOCK(stp, 31 << 6);
    PV_BLOCK(vts[1]);
  }

  lrun += __shfl_xor(lrun, 16);
  lrun += __shfl_xor(lrun, 32);
  float inv = 1.f / lrun;
  int sq = q0 + lm;
  float* ob = outp + ((size_t)(b * 2048 + sq)) * 1024 + h * 64;
#pragma unroll
  for (int dt = 0; dt < 4; ++dt) {
    f32x4 o;
#pragma unroll
    for (int r = 0; r < 4; ++r) o[r] = ctx[dt][r] * inv;
    *(f32x4*)(ob + dt * 16 + g * 4) = o;
  }
#undef QK_BLOCK
#undef SM_BLOCK
#undef PV_BLOCK
}

extern "C" void kernel_launch(void* const* d_in, const int* in_sizes, int n_in,
                              void* d_out, int out_size, void* d_ws, size_t ws_size,
                              hipStream_t stream) {
  const float* hs   = (const float*)d_in[0];
  const float* mask = (const float*)d_in[1];
  const float* Wq   = (const float*)d_in[2];
  const float* bq   = (const float*)d_in[3];
  const float* Wk   = (const float*)d_in[4];
  const float* bk   = (const float*)d_in[5];
  const float* Wv   = (const float*)d_in[6];
  const float* bv   = (const float*)d_in[7];
  float* out = (float*)d_out;

  char* ws = (char*)d_ws;
  u16* hsb = (u16*)(ws);                          // 16 MB: hs bf16 [8192][1024]
  u16* wt  = (u16*)(ws + (16u << 20));            //  6 MB: Wt bf16 [3][1024][1024]
  u16* Qb  = (u16*)(ws + (24u << 20));            // 16 MB: Q  [B][H][S][64]
  u16* Kb  = (u16*)(ws + (40u << 20));            // 16 MB: K  [B][H][S][64]
  u16* Vtb = (u16*)(ws + (56u << 20));            // 16 MB: Vt_perm [B][H][64][2048]

  cvt_hs_k<<<dim3(8192), dim3(256), 0, stream>>>(hs, hsb, 8388608);
  twk<<<dim3(16, 16, 3), dim3(256), 0, stream>>>(Wq, Wk, Wv, wt);
  qkv_gemm_k<<<dim3(24, 64), dim3(256), 0, stream>>>(hsb, wt, bq, bk, bv, Qb, Kb, Vtb);
  attn_k<<<dim3(16, 64), dim3(512), 0, stream>>>(Qb, Kb, Vtb, mask, out);
}